// Round 1
// baseline (498.558 us; speedup 1.0000x reference)
//
#include <hip/hip_runtime.h>
#include <math.h>

#define DM   1024
#define DS   64
#define BATCH 8
#define SEQ  2048
#define CL   32          // chunk length
#define NC   64          // number of chunks (SEQ/CL)

// ---------------------------------------------------------------------------
// Kernel A: fused projections.
//   delta = softplus(x @ W_delta^T + b_delta)
//   u     = (x @ W_Bp^T + b_Bp) * x[:, :, :64]
//   ct    =  x @ W_Cp^T + b_Cp
// Block: 8 rows of x, 256 threads. Thread = (r = tid&7, oc = tid>>3),
// computes 6 outputs o = oc + 32*m (covers 192 = 3 mats x 64 cols).
// x row staged in LDS with stride 1028 (pad 4) -> bank = (4r+k)%32, the 8
// distinct r per wave hit 8 distinct banks (conflict-free).
// ---------------------------------------------------------------------------
__global__ __launch_bounds__(256) void proj_kernel(
    const float* __restrict__ x,
    const float* __restrict__ Wd, const float* __restrict__ bd,
    const float* __restrict__ Wb, const float* __restrict__ bb,
    const float* __restrict__ Wc, const float* __restrict__ bc,
    float* __restrict__ delta_g, float* __restrict__ u_g,
    float* __restrict__ ct_g)
{
    __shared__ float s_x[8 * 1028];                   // 32.9 KB
    const int tid  = threadIdx.x;
    const int row0 = blockIdx.x * 8;

    // stage 8 rows x 1024 floats (2048 float4, 8 per thread), coalesced
    const float4* xg = (const float4*)(x + (size_t)row0 * DM);
    #pragma unroll
    for (int it = 0; it < 8; ++it) {
        int f  = tid + it * 256;                      // float4 index 0..2047
        int r  = f >> 8;                              // 256 float4 per row
        int kf = f & 255;
        float4 v = xg[r * 256 + kf];
        *(float4*)(s_x + r * 1028 + kf * 4) = v;
    }
    __syncthreads();

    const int r  = tid & 7;
    const int oc = tid >> 3;                          // 0..31
    const float* xr = s_x + r * 1028;

    const float* wrow[6];
    #pragma unroll
    for (int m = 0; m < 6; ++m) {
        int o = oc + (m << 5);                        // 0..191
        const float* W = (o < 64) ? Wd : (o < 128 ? Wb : Wc);
        wrow[m] = W + (size_t)(o & 63) * DM;
    }

    float acc[6] = {0.f, 0.f, 0.f, 0.f, 0.f, 0.f};
    for (int k = 0; k < DM; k += 4) {
        float4 xv = *(const float4*)(xr + k);
        #pragma unroll
        for (int m = 0; m < 6; ++m) {
            float4 wv = *(const float4*)(wrow[m] + k);
            acc[m] += xv.x * wv.x + xv.y * wv.y + xv.z * wv.z + xv.w * wv.w;
        }
    }

    const int row = row0 + r;
    #pragma unroll
    for (int m = 0; m < 6; ++m) {
        int o   = oc + (m << 5);
        int mat = o >> 6;
        int col = o & 63;
        if (mat == 0) {
            float z  = acc[m] + bd[col];
            float sp = (z > 20.f) ? z : log1pf(__expf(z));
            delta_g[(size_t)row * DS + col] = sp;
        } else if (mat == 1) {
            float z = acc[m] + bb[col];
            u_g[(size_t)row * DS + col] = z * xr[col];  // Bt * x[:, :, :64]
        } else {
            float z = acc[m] + bc[col];
            ct_g[(size_t)row * DS + col] = z;
        }
    }
}

// ---------------------------------------------------------------------------
// Kernel B (pass 1): per-chunk local recurrence from h=0.
// Block = (chunk c, batch b), 256 threads: thread owns row i = tid&63 and
// 16 columns j in [jg*16, jg*16+16), jg = tid>>6.
// Outputs: E[c,b,i,j] = local end state; Dsum[c,b,i] = sum_t delta.
// (chunk decay product = exp(A_log[i,j] * Dsum) -- exact in exact arith)
// ---------------------------------------------------------------------------
__global__ __launch_bounds__(256) void pass1_kernel(
    const float* __restrict__ delta_g, const float* __restrict__ u_g,
    const float* __restrict__ A_log,
    float* __restrict__ E, float* __restrict__ Dsum)
{
    __shared__ float s_d[CL * 64];
    __shared__ float s_u[CL * 64];
    const int c = blockIdx.x, b = blockIdx.y, tid = threadIdx.x;
    const int t0 = c * CL;

    const float4* dg = (const float4*)(delta_g + ((size_t)b * SEQ + t0) * DS);
    const float4* ug = (const float4*)(u_g     + ((size_t)b * SEQ + t0) * DS);
    #pragma unroll
    for (int it = 0; it < (CL * 64 / 4) / 256; ++it) {
        int f = tid + it * 256;
        ((float4*)s_d)[f] = dg[f];
        ((float4*)s_u)[f] = ug[f];
    }

    const int i  = tid & 63;
    const int jg = tid >> 6;
    float alog[16];
    {
        const float4* ar = (const float4*)(A_log + i * 64 + jg * 16);
        #pragma unroll
        for (int q = 0; q < 4; ++q) {
            float4 v = ar[q];
            alog[4*q+0] = v.x; alog[4*q+1] = v.y;
            alog[4*q+2] = v.z; alog[4*q+3] = v.w;
        }
    }
    __syncthreads();

    float h[16];
    #pragma unroll
    for (int k = 0; k < 16; ++k) h[k] = 0.f;
    float dsum = 0.f;

    for (int t = 0; t < CL; ++t) {
        float d = s_d[t * 64 + i];
        dsum += d;
        const float* up = s_u + t * 64 + jg * 16;     // wave-uniform: broadcast
        #pragma unroll
        for (int k = 0; k < 16; ++k)
            h[k] = __expf(alog[k] * d) * h[k] + up[k];
    }

    float* eo = E + (((size_t)c * BATCH + b) * 64 + i) * 64 + jg * 16;
    #pragma unroll
    for (int q = 0; q < 4; ++q)
        ((float4*)eo)[q] = make_float4(h[4*q], h[4*q+1], h[4*q+2], h[4*q+3]);
    if (jg == 0) Dsum[((size_t)c * BATCH + b) * 64 + i] = dsum;
}

// ---------------------------------------------------------------------------
// Kernel C (pass 2): sequential scan over chunks, parallel over B*64*64
// elements. Sin[c] = state entering chunk c.
//   carry_{c+1} = exp(A_log * Dsum[c]) * carry_c + E[c]
// ---------------------------------------------------------------------------
__global__ __launch_bounds__(256) void pass2_kernel(
    const float* __restrict__ A_log, const float* __restrict__ E,
    const float* __restrict__ Dsum, float* __restrict__ Sin)
{
    const int g = blockIdx.x * 256 + threadIdx.x;     // 0..32767
    const int b = g >> 12;                            // g / 4096
    const int e = g & 4095;                           // i*64 + j
    const int i = e >> 6;
    const float al = A_log[e];
    float carry = 0.f;
    for (int c = 0; c < NC; ++c) {
        const size_t base = ((size_t)c * BATCH + b) * 4096;
        Sin[base + e] = carry;
        carry = __expf(al * Dsum[((size_t)c * BATCH + b) * 64 + i]) * carry
                + E[base + e];
    }
}

// ---------------------------------------------------------------------------
// Kernel D (pass 3): replay each chunk from its true incoming state and emit
//   y[b,t,i] = sum_j Ct[b,t,j] * h[b,i,j]
// Reduction over j: thread computes 16-j partial in-register, 4-way combine
// through double-buffered LDS (1 barrier per step).
// ---------------------------------------------------------------------------
__global__ __launch_bounds__(256) void pass3_kernel(
    const float* __restrict__ delta_g, const float* __restrict__ u_g,
    const float* __restrict__ ct_g, const float* __restrict__ A_log,
    const float* __restrict__ Sin, float* __restrict__ out)
{
    __shared__ float s_d[CL * 64];
    __shared__ float s_u[CL * 64];
    __shared__ float s_c[CL * 64];
    __shared__ float ypart[2][4][64];

    const int c = blockIdx.x, b = blockIdx.y, tid = threadIdx.x;
    const int t0 = c * CL;

    const float4* dg = (const float4*)(delta_g + ((size_t)b * SEQ + t0) * DS);
    const float4* ug = (const float4*)(u_g     + ((size_t)b * SEQ + t0) * DS);
    const float4* cg = (const float4*)(ct_g    + ((size_t)b * SEQ + t0) * DS);
    #pragma unroll
    for (int it = 0; it < (CL * 64 / 4) / 256; ++it) {
        int f = tid + it * 256;
        ((float4*)s_d)[f] = dg[f];
        ((float4*)s_u)[f] = ug[f];
        ((float4*)s_c)[f] = cg[f];
    }

    const int i  = tid & 63;
    const int jg = tid >> 6;
    float alog[16];
    {
        const float4* ar = (const float4*)(A_log + i * 64 + jg * 16);
        #pragma unroll
        for (int q = 0; q < 4; ++q) {
            float4 v = ar[q];
            alog[4*q+0] = v.x; alog[4*q+1] = v.y;
            alog[4*q+2] = v.z; alog[4*q+3] = v.w;
        }
    }

    float h[16];
    {
        const float4* hin = (const float4*)(
            Sin + (((size_t)c * BATCH + b) * 64 + i) * 64 + jg * 16);
        #pragma unroll
        for (int q = 0; q < 4; ++q) {
            float4 v = hin[q];
            h[4*q+0] = v.x; h[4*q+1] = v.y; h[4*q+2] = v.z; h[4*q+3] = v.w;
        }
    }
    __syncthreads();

    int buf = 0;
    for (int t = 0; t < CL; ++t) {
        float d = s_d[t * 64 + i];
        const float* up = s_u + t * 64 + jg * 16;
        const float* cp = s_c + t * 64 + jg * 16;
        float part = 0.f;
        #pragma unroll
        for (int k = 0; k < 16; ++k) {
            h[k] = __expf(alog[k] * d) * h[k] + up[k];
            part += cp[k] * h[k];
        }
        ypart[buf][jg][i] = part;
        __syncthreads();
        if (tid < 64) {
            float y = ypart[buf][0][tid] + ypart[buf][1][tid]
                    + ypart[buf][2][tid] + ypart[buf][3][tid];
            out[((size_t)b * SEQ + t0 + t) * DS + tid] = y;
        }
        buf ^= 1;
    }
}

// ---------------------------------------------------------------------------
// Inputs (setup_inputs order):
//  0:x 1:W_cog 2:b_cog 3:W_beh 4:b_beh 5:W_env 6:b_env
//  7:W_delta 8:b_delta 9:W_Bp 10:b_Bp 11:W_Cp 12:b_Cp 13:A_log
// cog/beh/env are dead code in the reference (A_t is deleted) -> unused.
// ---------------------------------------------------------------------------
extern "C" void kernel_launch(void* const* d_in, const int* in_sizes, int n_in,
                              void* d_out, int out_size, void* d_ws, size_t ws_size,
                              hipStream_t stream)
{
    const float* x     = (const float*)d_in[0];
    const float* Wd    = (const float*)d_in[7];
    const float* bd    = (const float*)d_in[8];
    const float* Wb    = (const float*)d_in[9];
    const float* bb    = (const float*)d_in[10];
    const float* Wc    = (const float*)d_in[11];
    const float* bc    = (const float*)d_in[12];
    const float* A_log = (const float*)d_in[13];
    float* out = (float*)d_out;

    float* ws = (float*)d_ws;
    float* delta_g = ws;                       // 1,048,576 floats
    float* u_g     = ws + 1 * 1048576;         // 1,048,576
    float* ct_g    = ws + 2 * 1048576;         // 1,048,576
    float* E       = ws + 3 * 1048576;         // NC*B*4096 = 2,097,152
    float* Sin     = ws + 5 * 1048576;         // 2,097,152
    float* Dsum    = ws + 7 * 1048576;         // NC*B*64 = 32,768

    proj_kernel<<<(BATCH * SEQ) / 8, 256, 0, stream>>>(
        x, Wd, bd, Wb, bb, Wc, bc, delta_g, u_g, ct_g);
    pass1_kernel<<<dim3(NC, BATCH), 256, 0, stream>>>(
        delta_g, u_g, A_log, E, Dsum);
    pass2_kernel<<<(BATCH * 4096) / 256, 256, 0, stream>>>(
        A_log, E, Dsum, Sin);
    pass3_kernel<<<dim3(NC, BATCH), 256, 0, stream>>>(
        delta_g, u_g, ct_g, A_log, Sin, out);
}

// Round 2
// 192.267 us; speedup vs baseline: 2.5931x; 2.5931x over previous
//
#include <hip/hip_runtime.h>
#include <math.h>

#define DM   1024
#define DS   64
#define BATCH 8
#define SEQ  2048
#define CL   32          // chunk length
#define NC   64          // number of chunks (SEQ/CL)

typedef __bf16 bf16x8 __attribute__((ext_vector_type(8)));
typedef __bf16 bf16x4 __attribute__((ext_vector_type(4)));
typedef float  f32x4  __attribute__((ext_vector_type(4)));

// ---------------------------------------------------------------------------
// Kernel W: pre-convert W_delta|W_Bp|W_Cp (each [64][1024] f32) into one
// packed bf16 buffer laid out K-tiled: Wp[(kt*192 + n)*32 + kk], n in 0..191,
// k = kt*32+kk. GEMM then stages a K-tile (192 rows x 64 B) with pure 16B
// loads, no conversion in the hot loop.
// ---------------------------------------------------------------------------
__global__ __launch_bounds__(256) void wconv_kernel(
    const float* __restrict__ Wd, const float* __restrict__ Wb,
    const float* __restrict__ Wc, __bf16* __restrict__ Wp)
{
    int idx = blockIdx.x * 256 + threadIdx.x;   // 0..196607 = n*1024 + k
    int k  = idx & 1023;
    int n  = idx >> 10;                          // 0..191
    const float* W = (n < 64) ? Wd : (n < 128 ? Wb : Wc);
    float v = W[(size_t)(n & 63) * DM + k];
    int kt = k >> 5, kk = k & 31;
    Wp[((size_t)kt * 192 + n) * 32 + kk] = (__bf16)v;
}

// ---------------------------------------------------------------------------
// Kernel A: MFMA projection.  C[16384 x 192] = x[16384 x 1024] @ Wp^T,
// split-precision: x = x_hi + x_lo (bf16 planes), W in bf16:
//   acc += x_hi*w + x_lo*w   (error ~ x * w_lo ~ 6e-4 std, negligible)
// Block: 32 M-rows x 192 N-cols, 256 threads (4 waves), grid 512 (2 blk/CU).
// Wave (wv): M-half = (wv&1)*16, N-half = (wv>>1)*96 -> 6 n-tiles of 16.
// K-loop: 32 tiles of K=32, register ping-pong prefetch (tile kt+1 issued
// before computing kt). LDS rows padded to 40 shorts (80 B: 16B-aligned,
// <=2-way bank aliasing on ds_read_b128).
// Epilogue fuses bias + softplus(delta) + u = Bt * x[:, :, :64].
// MFMA layouts (m89/m91-verified): A[m=lane&15][k=quad*8+j],
// B[n=lane&15][k=quad*8+j], D: col(n)=lane&15, row(m)=quad*4+reg.
// ---------------------------------------------------------------------------
__global__ __launch_bounds__(256) void proj_mfma(
    const float* __restrict__ x, const __bf16* __restrict__ Wp,
    const float* __restrict__ bd, const float* __restrict__ bb,
    const float* __restrict__ bc,
    float* __restrict__ delta_g, float* __restrict__ u_g,
    float* __restrict__ ct_g)
{
    __shared__ __bf16 sAh[32 * 40];
    __shared__ __bf16 sAl[32 * 40];
    __shared__ __bf16 sB[192 * 40];

    const int tid  = threadIdx.x;
    const int row0 = blockIdx.x * 32;            // M base (0..16352)

    // staging indices
    const int sx_row = tid >> 3;                 // 0..31
    const int sx_sub = tid & 7;                  // 0..7 (float4 within 32-K)
    const float* xg = x + (size_t)(row0 + sx_row) * DM + sx_sub * 4;
    const int wn0  = tid >> 2;                   // 0..63 (n, +64/+128 for q)
    const int wsub = tid & 3;                    // 0..3 (16B chunk within row)

    const int lane = tid & 63, wv = tid >> 6;
    const int l15 = lane & 15, quad = lane >> 4;
    const int mrow  = (wv & 1) * 16;             // wave M base within tile
    const int nbase = (wv >> 1) * 96;            // wave N base

    f32x4 acc[6];
    #pragma unroll
    for (int i = 0; i < 6; ++i) acc[i] = (f32x4){0.f, 0.f, 0.f, 0.f};

    float4 xA, xB;
    uint4 wA0, wA1, wA2, wB0, wB1, wB2;

    #define LOADX(dst, kt)  dst = *(const float4*)(xg + (kt) * 32)
    #define LOADW(d0, d1, d2, kt) do {                                        \
        const __bf16* wp = Wp + ((size_t)(kt) * 192) * 32 + wsub * 8;         \
        d0 = *(const uint4*)(wp + (size_t)(wn0      ) * 32);                  \
        d1 = *(const uint4*)(wp + (size_t)(wn0 +  64) * 32);                  \
        d2 = *(const uint4*)(wp + (size_t)(wn0 + 128) * 32);                  \
    } while (0)

    #define STAGE(xc, w0, w1, w2) do {                                        \
        __bf16 h0 = (__bf16)xc.x, h1 = (__bf16)xc.y,                          \
               h2 = (__bf16)xc.z, h3 = (__bf16)xc.w;                          \
        bf16x4 hv = {h0, h1, h2, h3};                                         \
        bf16x4 lv = {(__bf16)(xc.x - (float)h0), (__bf16)(xc.y - (float)h1),  \
                     (__bf16)(xc.z - (float)h2), (__bf16)(xc.w - (float)h3)}; \
        *(bf16x4*)&sAh[sx_row * 40 + sx_sub * 4] = hv;                        \
        *(bf16x4*)&sAl[sx_row * 40 + sx_sub * 4] = lv;                        \
        *(uint4*)&sB[(wn0      ) * 40 + wsub * 8] = w0;                       \
        *(uint4*)&sB[(wn0 +  64) * 40 + wsub * 8] = w1;                       \
        *(uint4*)&sB[(wn0 + 128) * 40 + wsub * 8] = w2;                       \
    } while (0)

    #define COMPUTE() do {                                                    \
        bf16x8 ah = *(const bf16x8*)&sAh[(mrow + l15) * 40 + quad * 8];       \
        bf16x8 al = *(const bf16x8*)&sAl[(mrow + l15) * 40 + quad * 8];       \
        _Pragma("unroll")                                                     \
        for (int nt = 0; nt < 6; ++nt) {                                      \
            bf16x8 bf = *(const bf16x8*)                                      \
                &sB[(nbase + nt * 16 + l15) * 40 + quad * 8];                 \
            acc[nt] = __builtin_amdgcn_mfma_f32_16x16x32_bf16(                \
                ah, bf, acc[nt], 0, 0, 0);                                    \
            acc[nt] = __builtin_amdgcn_mfma_f32_16x16x32_bf16(                \
                al, bf, acc[nt], 0, 0, 0);                                    \
        }                                                                     \
    } while (0)

    LOADX(xA, 0);
    LOADW(wA0, wA1, wA2, 0);

    for (int kt = 0; kt < 32; kt += 2) {
        LOADX(xB, kt + 1);
        LOADW(wB0, wB1, wB2, kt + 1);
        STAGE(xA, wA0, wA1, wA2);
        __syncthreads();
        COMPUTE();
        __syncthreads();
        if (kt + 2 < 32) {
            LOADX(xA, kt + 2);
            LOADW(wA0, wA1, wA2, kt + 2);
        }
        STAGE(xB, wB0, wB1, wB2);
        __syncthreads();
        COMPUTE();
        __syncthreads();
    }

    // epilogue: bias + activations + stores
    #pragma unroll
    for (int nt = 0; nt < 6; ++nt) {
        int gn  = nbase + nt * 16 + l15;        // 0..191
        int mat = gn >> 6;                      // wave-uniform per nt
        int col = gn & 63;
        float bias = (mat == 0) ? bd[col] : (mat == 1 ? bb[col] : bc[col]);
        #pragma unroll
        for (int r = 0; r < 4; ++r) {
            int m = row0 + mrow + quad * 4 + r;
            float v = acc[nt][r] + bias;
            if (mat == 0) {
                float sp = (v > 20.f) ? v : log1pf(__expf(v));
                delta_g[(size_t)m * DS + col] = sp;
            } else if (mat == 1) {
                u_g[(size_t)m * DS + col] = v * x[(size_t)m * DM + col];
            } else {
                ct_g[(size_t)m * DS + col] = v;
            }
        }
    }
    #undef LOADX
    #undef LOADW
    #undef STAGE
    #undef COMPUTE
}

// ---------------------------------------------------------------------------
// Kernel B (pass 1): per-chunk local recurrence from h=0.
// ---------------------------------------------------------------------------
__global__ __launch_bounds__(256) void pass1_kernel(
    const float* __restrict__ delta_g, const float* __restrict__ u_g,
    const float* __restrict__ A_log,
    float* __restrict__ E, float* __restrict__ Dsum)
{
    __shared__ float s_d[CL * 64];
    __shared__ float s_u[CL * 64];
    const int c = blockIdx.x, b = blockIdx.y, tid = threadIdx.x;
    const int t0 = c * CL;

    const float4* dg = (const float4*)(delta_g + ((size_t)b * SEQ + t0) * DS);
    const float4* ug = (const float4*)(u_g     + ((size_t)b * SEQ + t0) * DS);
    #pragma unroll
    for (int it = 0; it < (CL * 64 / 4) / 256; ++it) {
        int f = tid + it * 256;
        ((float4*)s_d)[f] = dg[f];
        ((float4*)s_u)[f] = ug[f];
    }

    const int i  = tid & 63;
    const int jg = tid >> 6;
    float alog[16];
    {
        const float4* ar = (const float4*)(A_log + i * 64 + jg * 16);
        #pragma unroll
        for (int q = 0; q < 4; ++q) {
            float4 v = ar[q];
            alog[4*q+0] = v.x; alog[4*q+1] = v.y;
            alog[4*q+2] = v.z; alog[4*q+3] = v.w;
        }
    }
    __syncthreads();

    float h[16];
    #pragma unroll
    for (int k = 0; k < 16; ++k) h[k] = 0.f;
    float dsum = 0.f;

    for (int t = 0; t < CL; ++t) {
        float d = s_d[t * 64 + i];
        dsum += d;
        const float* up = s_u + t * 64 + jg * 16;
        #pragma unroll
        for (int k = 0; k < 16; ++k)
            h[k] = __expf(alog[k] * d) * h[k] + up[k];
    }

    float* eo = E + (((size_t)c * BATCH + b) * 64 + i) * 64 + jg * 16;
    #pragma unroll
    for (int q = 0; q < 4; ++q)
        ((float4*)eo)[q] = make_float4(h[4*q], h[4*q+1], h[4*q+2], h[4*q+3]);
    if (jg == 0) Dsum[((size_t)c * BATCH + b) * 64 + i] = dsum;
}

// ---------------------------------------------------------------------------
// Kernel C (pass 2): sequential scan over chunks, parallel over B*64*64.
// ---------------------------------------------------------------------------
__global__ __launch_bounds__(256) void pass2_kernel(
    const float* __restrict__ A_log, const float* __restrict__ E,
    const float* __restrict__ Dsum, float* __restrict__ Sin)
{
    const int g = blockIdx.x * 256 + threadIdx.x;     // 0..32767
    const int b = g >> 12;
    const int e = g & 4095;
    const int i = e >> 6;
    const float al = A_log[e];
    float carry = 0.f;
    for (int c = 0; c < NC; ++c) {
        const size_t base = ((size_t)c * BATCH + b) * 4096;
        Sin[base + e] = carry;
        carry = __expf(al * Dsum[((size_t)c * BATCH + b) * 64 + i]) * carry
                + E[base + e];
    }
}

// ---------------------------------------------------------------------------
// Kernel D (pass 3): replay each chunk from its true incoming state, emit
//   y[b,t,i] = sum_j Ct[b,t,j] * h[b,i,j]
// ---------------------------------------------------------------------------
__global__ __launch_bounds__(256) void pass3_kernel(
    const float* __restrict__ delta_g, const float* __restrict__ u_g,
    const float* __restrict__ ct_g, const float* __restrict__ A_log,
    const float* __restrict__ Sin, float* __restrict__ out)
{
    __shared__ float s_d[CL * 64];
    __shared__ float s_u[CL * 64];
    __shared__ float s_c[CL * 64];
    __shared__ float ypart[2][4][64];

    const int c = blockIdx.x, b = blockIdx.y, tid = threadIdx.x;
    const int t0 = c * CL;

    const float4* dg = (const float4*)(delta_g + ((size_t)b * SEQ + t0) * DS);
    const float4* ug = (const float4*)(u_g     + ((size_t)b * SEQ + t0) * DS);
    const float4* cg = (const float4*)(ct_g    + ((size_t)b * SEQ + t0) * DS);
    #pragma unroll
    for (int it = 0; it < (CL * 64 / 4) / 256; ++it) {
        int f = tid + it * 256;
        ((float4*)s_d)[f] = dg[f];
        ((float4*)s_u)[f] = ug[f];
        ((float4*)s_c)[f] = cg[f];
    }

    const int i  = tid & 63;
    const int jg = tid >> 6;
    float alog[16];
    {
        const float4* ar = (const float4*)(A_log + i * 64 + jg * 16);
        #pragma unroll
        for (int q = 0; q < 4; ++q) {
            float4 v = ar[q];
            alog[4*q+0] = v.x; alog[4*q+1] = v.y;
            alog[4*q+2] = v.z; alog[4*q+3] = v.w;
        }
    }

    float h[16];
    {
        const float4* hin = (const float4*)(
            Sin + (((size_t)c * BATCH + b) * 64 + i) * 64 + jg * 16);
        #pragma unroll
        for (int q = 0; q < 4; ++q) {
            float4 v = hin[q];
            h[4*q+0] = v.x; h[4*q+1] = v.y; h[4*q+2] = v.z; h[4*q+3] = v.w;
        }
    }
    __syncthreads();

    int buf = 0;
    for (int t = 0; t < CL; ++t) {
        float d = s_d[t * 64 + i];
        const float* up = s_u + t * 64 + jg * 16;
        const float* cp = s_c + t * 64 + jg * 16;
        float part = 0.f;
        #pragma unroll
        for (int k = 0; k < 16; ++k) {
            h[k] = __expf(alog[k] * d) * h[k] + up[k];
            part += cp[k] * h[k];
        }
        ypart[buf][jg][i] = part;
        __syncthreads();
        if (tid < 64) {
            float y = ypart[buf][0][tid] + ypart[buf][1][tid]
                    + ypart[buf][2][tid] + ypart[buf][3][tid];
            out[((size_t)b * SEQ + t0 + t) * DS + tid] = y;
        }
        buf ^= 1;
    }
}

// ---------------------------------------------------------------------------
// Inputs: 0:x 1..6:(cog/beh/env dead) 7:W_delta 8:b_delta 9:W_Bp 10:b_Bp
//         11:W_Cp 12:b_Cp 13:A_log
// ---------------------------------------------------------------------------
extern "C" void kernel_launch(void* const* d_in, const int* in_sizes, int n_in,
                              void* d_out, int out_size, void* d_ws, size_t ws_size,
                              hipStream_t stream)
{
    const float* x     = (const float*)d_in[0];
    const float* Wd    = (const float*)d_in[7];
    const float* bd    = (const float*)d_in[8];
    const float* Wb    = (const float*)d_in[9];
    const float* bb    = (const float*)d_in[10];
    const float* Wc    = (const float*)d_in[11];
    const float* bc    = (const float*)d_in[12];
    const float* A_log = (const float*)d_in[13];
    float* out = (float*)d_out;

    float* ws = (float*)d_ws;
    float* delta_g = ws;                       // 1,048,576 floats
    float* u_g     = ws + 1 * 1048576;         // 1,048,576
    float* ct_g    = ws + 2 * 1048576;         // 1,048,576
    float* E       = ws + 3 * 1048576;         // 2,097,152 (pass1 output)
    float* Sin     = ws + 5 * 1048576;         // 2,097,152
    float* Dsum    = ws + 7 * 1048576;         // 32,768
    // W_packed aliases E's region: only live during wconv+proj (before pass1
    // writes E). 196608 bf16 = 384 KB << 8 MB region.
    __bf16* Wp     = (__bf16*)E;

    wconv_kernel<<<768, 256, 0, stream>>>(Wd, Wb, Wc, Wp);
    proj_mfma<<<512, 256, 0, stream>>>(
        x, Wp, bd, bb, bc, delta_g, u_g, ct_g);
    pass1_kernel<<<dim3(NC, BATCH), 256, 0, stream>>>(
        delta_g, u_g, A_log, E, Dsum);
    pass2_kernel<<<(BATCH * 4096) / 256, 256, 0, stream>>>(
        A_log, E, Dsum, Sin);
    pass3_kernel<<<dim3(NC, BATCH), 256, 0, stream>>>(
        delta_g, u_g, ct_g, A_log, Sin, out);
}